// Round 10
// baseline (926.584 us; speedup 1.0000x reference)
//
#include <hip/hip_runtime.h>

// GraphSAGE encoder, restructured: aggregate AFTER linear maps; BN folded into W1.
//   N=50000, G=2000, E=800000, H=512, Z=64
// GEMM1: reads x f32 directly (conv fused in): 256x256 tile, 3-ring LDS pipeline,
//        A reg-staged (load f32 -> cvt bf16 -> ds_write), B via global_load_lds,
//        counted vmcnt(6), 1 barrier/iter, conflict-free granule swizzle,
//        XCD swizzle, setprio. NT=63 (K tail handled by BT zero-padding).
// prep_fused: BT1(BN-folded) + BT2 + b1' + degree-count in one launch.
// agg1/GEMM2/agg2: bf16 dataflow, fp32 accumulation.

#define BN_EPS 1e-5f
#define GK 2000      // K of GEMM1
#define KP 2048      // padded K of BT
#define NT1 63       // ceil(2000/32)
#define NT2 16       // 512/32

typedef __attribute__((ext_vector_type(8))) short bf16x8;
typedef __attribute__((ext_vector_type(4))) float f32x4;
typedef unsigned short u16x8 __attribute__((ext_vector_type(8)));

__device__ inline unsigned short f2bf(float f) {
    union { float f; unsigned u; } v; v.f = f;
    unsigned r = (v.u + 0x7fffu + ((v.u >> 16) & 1u)) >> 16;
    return (unsigned short)r;
}
__device__ inline float bf2f(unsigned short u) {
    union { unsigned u; float f; } v; v.u = ((unsigned)u) << 16;
    return v.f;
}

#define GLL16(gp, lp) __builtin_amdgcn_global_load_lds( \
    (const __attribute__((address_space(1))) void*)(gp), \
    (__attribute__((address_space(3))) void*)(lp), 16, 0, 0)

// ---------------- fused prep: BT1 (BN-folded) | BT2 | b1' | degree count --------
// blocks [0,1024): BT1; [1024,1056): BT2; 1056: b1'; [1057,2081): count.
__global__ __launch_bounds__(256) void prep_fused(
    const float* __restrict__ W1l, const float* __restrict__ W1r,
    const float* __restrict__ gamma, const float* __restrict__ beta,
    const float* __restrict__ mean, const float* __restrict__ var,
    const float* __restrict__ b1, unsigned short* __restrict__ BT,
    const float* __restrict__ W2l, const float* __restrict__ W2r,
    unsigned short* __restrict__ BT2, float* __restrict__ b1p,
    const int* __restrict__ ei, int* __restrict__ cnt, int E)
{
    const int bb = blockIdx.x;
    if (bb < 1024) {
        // BT1[1024][2048] = ([W1l|W1r]*diag(sc))^T, zero-padded k>=2000
        int idx = bb * 256 + threadIdx.x;
        int c  = idx >> 8;
        int k0 = (idx & 255) << 3;
        int cc = (c < 512) ? c : c - 512;
        float scv = gamma[cc] * rsqrtf(var[cc] + BN_EPS);
        const float* W = (c < 512) ? (W1l + cc) : (W1r + cc);
        unsigned short us[8];
#pragma unroll
        for (int j = 0; j < 8; ++j) {
            int k = k0 + j;
            float v = (k < GK) ? W[(size_t)k * 512] * scv : 0.0f;
            us[j] = f2bf(v);
        }
        *(u16x8*)&BT[(size_t)c * KP + k0] = *(u16x8*)us;
    } else if (bb < 1056) {
        // BT2[128][512] = [W2l|W2r]^T
        int idx = (bb - 1024) * 256 + threadIdx.x;
        int c  = idx >> 6;
        int k0 = (idx & 63) << 3;
        const float* W = (c < 64) ? (W2l + c) : (W2r + (c - 64));
        unsigned short us[8];
#pragma unroll
        for (int j = 0; j < 8; ++j) us[j] = f2bf(W[(size_t)(k0 + j) * 64]);
        *(u16x8*)&BT2[(size_t)c * 512 + k0] = *(u16x8*)us;
    } else if (bb == 1056) {
        // b1'[512] = b1*sc + (beta - mean*sc)
#pragma unroll
        for (int h = 0; h < 2; ++h) {
            int c = threadIdx.x + h * 256;
            float scv = gamma[c] * rsqrtf(var[c] + BN_EPS);
            b1p[c] = b1[c] * scv + (beta[c] - mean[c] * scv);
        }
    } else {
        // degree histogram (dst = ei[1][i])
        for (int i = (bb - 1057) * 256 + threadIdx.x; i < E; i += 1024 * 256)
            atomicAdd(&cnt[ei[E + i]], 1);
    }
}

// ---------------- exclusive scan over N counts (single block) ----------------
__global__ __launch_bounds__(1024) void scan_kernel(const int* __restrict__ cnt,
                                                    int* __restrict__ row_start, int n) {
    __shared__ int part[1024];
    int t = threadIdx.x;
    int chunk = (n + 1023) >> 10;
    int lo = t * chunk;
    int hi = lo + chunk; if (hi > n) hi = n;
    int s = 0;
    for (int i = lo; i < hi; ++i) s += cnt[i];
    part[t] = s;
    __syncthreads();
    for (int off = 1; off < 1024; off <<= 1) {
        int add = (t >= off) ? part[t - off] : 0;
        __syncthreads();
        part[t] += add;
        __syncthreads();
    }
    int run = (t == 0) ? 0 : part[t - 1];
    for (int i = lo; i < hi; ++i) { row_start[i] = run; run += cnt[i]; }
    if (t == 1023) row_start[n] = part[1023];
}

// ---------------- CSR fill (consumes cnt via atomicSub) ----------------
__global__ void fill_kernel(const int* __restrict__ ei, int E,
                            const int* __restrict__ row_start,
                            int* __restrict__ cnt, int* __restrict__ colidx) {
    int i = blockIdx.x * blockDim.x + threadIdx.x;
    if (i < E) {
        int d = ei[E + i];
        int p = atomicSub(&cnt[d], 1) - 1;
        colidx[row_start[d] + p] = ei[i];   // src
    }
}

// ---------------- GEMM1: Y = x(f32) @ BT^T — fused cvt, 256x256, 3-ring ---------
// Per iter it: [cvt A(it) regs -> bf16 -> ds_write As[rb]] -> vmcnt(6) ->
// lgkmcnt(0) -> s_barrier -> ds_read frags -> [issue 4 A-loads + 2 B-GLL for
// it+2] -> 32 MFMA. A-reg sets alternate by parity (static indexing).
__global__ __launch_bounds__(512) void gemm1_256(
    const float* __restrict__ x, int M,
    const unsigned short* __restrict__ BT,
    unsigned short* __restrict__ Y)
{
    __shared__ __align__(16) unsigned short As[3][8192];   // 256 rows x 32 k
    __shared__ __align__(16) unsigned short Bs[3][8192];   // 256 cols x 32 k

    const int t = threadIdx.x, wid = t >> 6, lane = t & 63;
    const int nbr = (M + 255) >> 8;
    const int nwg = nbr * 4;
    const int b   = blockIdx.x;
    int swz;
    if ((nwg & 7) == 0) swz = (b & 7) * (nwg >> 3) + (b >> 3);
    else swz = b;
    const int row0 = (swz >> 2) << 8;
    const int col0 = (swz & 3) << 8;

    // chunks c (16B LDS granule): c in {t, t+512}; row=c>>2, slot=c&3,
    // logical granule g = (c&3)^((c>>3)&3); source f32 offset gf = g*8.
    const int c0 = t, c1 = t + 512;
    const int gf0 = ((c0 & 3) ^ ((c0 >> 3) & 3)) << 3;   // f32 elems
    const int gf1 = ((c1 & 3) ^ ((c1 >> 3) & 3)) << 3;
    int ra0 = row0 + (c0 >> 2); if (ra0 >= M) ra0 = M - 1;
    int ra1 = row0 + (c1 >> 2); if (ra1 >= M) ra1 = M - 1;
    const float* aR0 = x + (size_t)ra0 * GK + gf0;
    const float* aR1 = x + (size_t)ra1 * GK + gf1;
    const int omax0 = 1992 - gf0;   // clamp keeps reads in-row; BT zeros kill tail
    const int omax1 = 1992 - gf1;
    const unsigned short* bS0 = BT + (size_t)(col0 + (c0 >> 2)) * KP + (gf0);
    const unsigned short* bS1 = BT + (size_t)(col0 + (c1 >> 2)) * KP + (gf1);

    const int wr = wid >> 2, wc = wid & 3;   // 2 x 4 wave grid
    const int fr16 = lane & 15;
    const int gswr = ((lane >> 4) ^ ((fr16 >> 1) & 3)) << 4;   // read byte offset

    f32x4 acc[8][4];
#pragma unroll
    for (int m = 0; m < 8; ++m)
#pragma unroll
        for (int n = 0; n < 4; ++n) acc[m][n] = (f32x4)0.0f;

    float sa[16], sb[16];   // two A staging sets (parity-static)

#define LOADA(st, kt) do {                                                \
        int o0 = (kt) * 32; if (o0 > omax0) o0 = omax0;                   \
        int o1 = (kt) * 32; if (o1 > omax1) o1 = omax1;                   \
        const float4* p0 = (const float4*)(aR0 + o0);                     \
        const float4* p1 = (const float4*)(aR1 + o1);                     \
        float4 u0 = p0[0], u1 = p0[1], u2 = p1[0], u3 = p1[1];            \
        st[0]=u0.x; st[1]=u0.y; st[2]=u0.z;  st[3]=u0.w;                  \
        st[4]=u1.x; st[5]=u1.y; st[6]=u1.z;  st[7]=u1.w;                  \
        st[8]=u2.x; st[9]=u2.y; st[10]=u2.z; st[11]=u2.w;                 \
        st[12]=u3.x; st[13]=u3.y; st[14]=u3.z; st[15]=u3.w;               \
    } while (0)

#define CVTW(st, buf) do {                                                \
        unsigned short us_[16];                                           \
        _Pragma("unroll")                                                 \
        for (int j_ = 0; j_ < 16; ++j_) us_[j_] = f2bf(st[j_]);           \
        unsigned short* ab_ = &As[buf][0];                                \
        *(u16x8*)(ab_ + c0 * 8) = *(u16x8*)&us_[0];                       \
        *(u16x8*)(ab_ + c1 * 8) = *(u16x8*)&us_[8];                       \
    } while (0)

#define STGB(kt, buf) do {                                                \
        unsigned short* bb_ = &Bs[buf][0];                                \
        GLL16(bS0 + (size_t)(kt) * 32, bb_ + c0 * 8);                     \
        GLL16(bS1 + (size_t)(kt) * 32, bb_ + c1 * 8);                     \
    } while (0)

    // prologue: A-loads + B-GLL for tiles 0 (set sa) and 1 (set sb): 12 VMEM
    LOADA(sa, 0); STGB(0, 0);
    LOADA(sb, 1); STGB(1, 1);

    int rb = 0;   // ring slot = it % 3
    for (int it = 0; it < NT1; ++it) {
        // convert + publish A(it) into As[rb] (regs loaded 2 iters ago)
        if ((it & 1) == 0) CVTW(sa, rb); else CVTW(sb, rb);

        // B(it) landed (counted: tile it+1's 6 stay in flight); my ds_writes done
        if (it == NT1 - 1) {
            asm volatile("s_waitcnt vmcnt(0)" ::: "memory");
        } else {
            asm volatile("s_waitcnt vmcnt(6)" ::: "memory");
        }
        asm volatile("s_waitcnt lgkmcnt(0)" ::: "memory");
        __builtin_amdgcn_s_barrier();
        __builtin_amdgcn_sched_barrier(0);

        const char* Ab = (const char*)&As[rb][0];
        const char* Bb = (const char*)&Bs[rb][0];
        bf16x8 af[8], bfr[4];
#pragma unroll
        for (int m = 0; m < 8; ++m)
            af[m] = *(const bf16x8*)(Ab + ((wr * 128 + m * 16 + fr16) << 6) + gswr);
#pragma unroll
        for (int n = 0; n < 4; ++n)
            bfr[n] = *(const bf16x8*)(Bb + ((wc * 64 + n * 16 + fr16) << 6) + gswr);

        // issue tile it+2: A -> reg set (same parity, just consumed), B -> LDS ring
        if (it + 2 < NT1) {
            int wb = rb + 2; if (wb >= 3) wb -= 3;
            if ((it & 1) == 0) LOADA(sa, it + 2); else LOADA(sb, it + 2);
            STGB(it + 2, wb);
        }

        __builtin_amdgcn_s_setprio(1);
#pragma unroll
        for (int m = 0; m < 8; ++m)
#pragma unroll
            for (int n = 0; n < 4; ++n)
                acc[m][n] = __builtin_amdgcn_mfma_f32_16x16x32_bf16(
                    af[m], bfr[n], acc[m][n], 0, 0, 0);
        __builtin_amdgcn_s_setprio(0);

        rb = (rb == 2) ? 0 : rb + 1;
    }
#undef LOADA
#undef CVTW
#undef STGB

    const int crow = (lane >> 4) << 2;
#pragma unroll
    for (int m = 0; m < 8; ++m) {
        int rbase = row0 + wr * 128 + m * 16 + crow;
#pragma unroll
        for (int r = 0; r < 4; ++r) {
            int row = rbase + r;
            if (row < M) {
                unsigned short* Yp = Y + (size_t)row * 1024 + col0 + wc * 64 + fr16;
#pragma unroll
                for (int n = 0; n < 4; ++n)
                    Yp[n * 16] = f2bf(acc[m][n][r]);
            }
        }
    }
}

// ---------------- agg1: mean-gather(Yl) + b1' + self(Yr) + ReLU -> h (bf16) ------
__global__ __launch_bounds__(256) void agg1_kernel(
    const unsigned short* __restrict__ Y, unsigned short* __restrict__ Hh,
    const int* __restrict__ row_start, const int* __restrict__ colidx,
    const float* __restrict__ b1p, int n)
{
    int wid  = (blockIdx.x * blockDim.x + threadIdx.x) >> 6;
    int lane = threadIdx.x & 63;
    if (wid >= n) return;
    int c0 = lane * 8;
    float bb[8];
    *(float4*)&bb[0] = *(const float4*)&b1p[c0];
    *(float4*)&bb[4] = *(const float4*)&b1p[c0 + 4];

    int s0 = row_start[wid], s1 = row_start[wid + 1];
    float acc[8] = {0, 0, 0, 0, 0, 0, 0, 0};
    int i = s0;
    for (; i + 2 <= s1; i += 2) {
        int src0 = colidx[i], src1 = colidx[i + 1];
        u16x8 v0 = *(const u16x8*)&Y[(size_t)src0 * 1024 + c0];
        u16x8 v1 = *(const u16x8*)&Y[(size_t)src1 * 1024 + c0];
#pragma unroll
        for (int j = 0; j < 8; ++j) acc[j] += bf2f(v0[j]) + bf2f(v1[j]);
    }
    if (i < s1) {
        int src = colidx[i];
        u16x8 v = *(const u16x8*)&Y[(size_t)src * 1024 + c0];
#pragma unroll
        for (int j = 0; j < 8; ++j) acc[j] += bf2f(v[j]);
    }
    float inv = 1.0f / fmaxf((float)(s1 - s0), 1.0f);
    u16x8 sv = *(const u16x8*)&Y[(size_t)wid * 1024 + 512 + c0];
    unsigned short o[8];
#pragma unroll
    for (int j = 0; j < 8; ++j) {
        float pre = acc[j] * inv + bb[j] + bf2f(sv[j]);
        o[j] = f2bf(fmaxf(pre, 0.0f));
    }
    *(u16x8*)&Hh[(size_t)wid * 512 + c0] = *(u16x8*)o;
}

// ---------------- GEMM2: U[M x 128](bf16) = h[M x 512](bf16) @ BT2^T ------------
__global__ __launch_bounds__(256) void gemm2_bf16(
    const unsigned short* __restrict__ Hh, int M,
    const unsigned short* __restrict__ BT2,
    unsigned short* __restrict__ U)
{
    __shared__ __align__(16) unsigned short As[2][128][32];
    __shared__ __align__(16) unsigned short Bs[2][128][32];

    const int t    = threadIdx.x;
    const int wid  = t >> 6;
    const int lane = t & 63;
    const int row0 = blockIdx.x << 7;

    const int c_lo = wid * 64 + lane;
    const int c_hi = c_lo + 256;
    const int s_lo = ((c_lo & 3) ^ ((c_lo >> 3) & 3)) << 3;
    const int s_hi = ((c_hi & 3) ^ ((c_hi >> 3) & 3)) << 3;
    int ra = row0 + (c_lo >> 2); if (ra >= M) ra = M - 1;
    int rbw = row0 + (c_hi >> 2); if (rbw >= M) rbw = M - 1;
    const unsigned short* aSrc0 = Hh + (size_t)ra * 512 + s_lo;
    const unsigned short* aSrc1 = Hh + (size_t)rbw * 512 + s_hi;
    const unsigned short* bSrc0 = BT2 + (size_t)(c_lo >> 2) * 512 + s_lo;
    const unsigned short* bSrc1 = BT2 + (size_t)(c_hi >> 2) * 512 + s_hi;

    const int wr   = wid >> 1, wc = wid & 1;
    const int fr16 = lane & 15;
    const int gsw2 = ((lane >> 4) ^ ((fr16 >> 1) & 3)) << 4;

    f32x4 acc[4][4];
#pragma unroll
    for (int m = 0; m < 4; ++m)
#pragma unroll
        for (int n = 0; n < 4; ++n) acc[m][n] = (f32x4)0.0f;

#define STAGE2(kt, buf) do {                                                  \
        int ko = (kt) * 32;                                                   \
        GLL16(aSrc0 + ko, (unsigned short*)&As[buf][0][0] + (size_t)c_lo * 8);  \
        GLL16(aSrc1 + ko, (unsigned short*)&As[buf][0][0] + (size_t)c_hi * 8);  \
        GLL16(bSrc0 + ko, (unsigned short*)&Bs[buf][0][0] + (size_t)c_lo * 8);  \
        GLL16(bSrc1 + ko, (unsigned short*)&Bs[buf][0][0] + (size_t)c_hi * 8);  \
    } while (0)

    STAGE2(0, 0);
    int cur = 0;
    for (int it = 0; it < NT2; ++it) {
        __syncthreads();
        if (it + 1 < NT2) STAGE2(it + 1, cur ^ 1);

        const char* Ab = (const char*)&As[cur][0][0];
        const char* Bb = (const char*)&Bs[cur][0][0];
        bf16x8 af[4], bfr[4];
#pragma unroll
        for (int m = 0; m < 4; ++m)
            af[m] = *(const bf16x8*)(Ab + ((wr * 64 + m * 16 + fr16) << 6) + gsw2);
#pragma unroll
        for (int n = 0; n < 4; ++n)
            bfr[n] = *(const bf16x8*)(Bb + ((wc * 64 + n * 16 + fr16) << 6) + gsw2);
#pragma unroll
        for (int m = 0; m < 4; ++m)
#pragma unroll
            for (int n = 0; n < 4; ++n)
                acc[m][n] = __builtin_amdgcn_mfma_f32_16x16x32_bf16(
                    af[m], bfr[n], acc[m][n], 0, 0, 0);
        cur ^= 1;
    }
#undef STAGE2

    const int crow = (lane >> 4) << 2;
#pragma unroll
    for (int m = 0; m < 4; ++m) {
        int rbase = row0 + wr * 64 + m * 16 + crow;
#pragma unroll
        for (int r = 0; r < 4; ++r) {
            int row = rbase + r;
            if (row < M) {
                unsigned short* Up = U + (size_t)row * 128 + wc * 64 + fr16;
#pragma unroll
                for (int n = 0; n < 4; ++n)
                    Up[n * 16] = f2bf(acc[m][n][r]);
            }
        }
    }
}

// ---------------- agg2: mean-gather(Ul) + b2 + self(Ur) -> out (f32) ----------------
__global__ __launch_bounds__(256) void agg2_kernel(
    const unsigned short* __restrict__ U,
    const int* __restrict__ row_start, const int* __restrict__ colidx,
    const float* __restrict__ b2, float* __restrict__ out, int n)
{
    int wid  = (blockIdx.x * blockDim.x + threadIdx.x) >> 6;
    int lane = threadIdx.x & 63;
    if (wid >= n) return;
    int s0 = row_start[wid], s1 = row_start[wid + 1];
    float acc = 0.f;
    int i = s0;
    for (; i + 2 <= s1; i += 2) {
        int src0 = colidx[i], src1 = colidx[i + 1];
        acc += bf2f(U[(size_t)src0 * 128 + lane]) + bf2f(U[(size_t)src1 * 128 + lane]);
    }
    if (i < s1) acc += bf2f(U[(size_t)colidx[i] * 128 + lane]);
    float inv = 1.0f / fmaxf((float)(s1 - s0), 1.0f);
    float z = acc * inv + b2[lane] + bf2f(U[(size_t)wid * 128 + 64 + lane]);
    out[(size_t)wid * 64 + lane] = z;
}

extern "C" void kernel_launch(void* const* d_in, const int* in_sizes, int n_in,
                              void* d_out, int out_size, void* d_ws, size_t ws_size,
                              hipStream_t stream) {
    const float* x     = (const float*)d_in[0];
    const int*   ei    = (const int*)d_in[1];
    const float* W1l   = (const float*)d_in[2];
    const float* b1    = (const float*)d_in[3];
    const float* W1r   = (const float*)d_in[4];
    const float* gamma = (const float*)d_in[5];
    const float* beta  = (const float*)d_in[6];
    const float* mean  = (const float*)d_in[7];
    const float* var   = (const float*)d_in[8];
    const float* W2l   = (const float*)d_in[9];
    const float* b2    = (const float*)d_in[10];
    const float* W2r   = (const float*)d_in[11];
    float* out = (float*)d_out;

    const int N = in_sizes[0] / 2000;   // 50000
    const int E = in_sizes[1] / 2;      // 800000
    const int nby = (N + 127) / 128;

    // Workspace layout (~161 MB; prior rounds prove ws >= 330 MB):
    //   Y [N*1024 bf16] | Hh [N*512 bf16] | BT [1024*2048 bf16] |
    //   BT2 [128*512 bf16] | b1p [512 f32] | cnt | row_start | colidx
    //   (U aliases Y after agg1)
    char* ws = (char*)d_ws;
    unsigned short* Y   = (unsigned short*)ws;
    unsigned short* Hh  = Y + (size_t)N * 1024;
    unsigned short* BT  = Hh + (size_t)N * 512;
    unsigned short* BT2 = BT + (size_t)1024 * KP;
    float* b1p     = (float*)(BT2 + (size_t)128 * 512);
    int* cnt       = (int*)(b1p + 512);
    int* row_start = cnt + N;
    int* colidx    = row_start + N + 4;
    unsigned short* U = Y;   // alias: Y dead after agg1

    hipMemsetAsync(cnt, 0, (size_t)N * sizeof(int), stream);

    prep_fused<<<2081, 256, 0, stream>>>(
        W1l, W1r, gamma, beta, mean, var, b1, BT, W2l, W2r, BT2, b1p,
        ei, cnt, E);

    scan_kernel<<<1, 1024, 0, stream>>>(cnt, row_start, N);
    int eb = (E + 255) / 256;
    fill_kernel<<<eb, 256, 0, stream>>>(ei, E, row_start, cnt, colidx);

    int nbr = (N + 255) / 256;
    gemm1_256<<<nbr * 4, 512, 0, stream>>>(x, N, BT, Y);
    agg1_kernel<<<(N + 3) / 4, 256, 0, stream>>>(
        Y, Hh, row_start, colidx, b1p, N);
    gemm2_bf16<<<nby, 256, 0, stream>>>(Hh, N, BT2, U);
    agg2_kernel<<<(N + 3) / 4, 256, 0, stream>>>(
        U, row_start, colidx, b2, out, N);
}

// Round 11
// 691.399 us; speedup vs baseline: 1.3402x; 1.3402x over previous
//
#include <hip/hip_runtime.h>
#include <hip/hip_bf16.h>

// GraphSAGE encoder, restructured: aggregate AFTER linear maps; BN folded into W1.
//   N=50000, G=2000, E=800000, H=512, Z=64
// GEMM1: reads x f32 directly. A staged via global_load_lds AS F32 (no reg
//        staging -> no compiler-wait serialization), converted to bf16 after
//        ds_read. 256x256 tile, 3-ring, counted vmcnt(6), 1 barrier/iter,
//        conflict-free 8-slot A swizzle + 4-slot B swizzle, XCD swizzle, setprio.
// prep_fused: BT1(BN-folded) + BT2 + b1' + degree-count in one launch (no conv!).
// agg1/GEMM2/agg2: bf16 dataflow, fp32 accumulation.

#define BN_EPS 1e-5f
#define GK 2000      // K of GEMM1
#define KP 2048      // padded K of BT
#define NT1 63       // ceil(2000/32)
#define NT2 16       // 512/32

typedef __attribute__((ext_vector_type(8))) short bf16x8;
typedef __attribute__((ext_vector_type(4))) float f32x4;
typedef unsigned short u16x8 __attribute__((ext_vector_type(8)));

__device__ inline unsigned short f2bf(float f) {
    union { float f; unsigned u; } v; v.f = f;
    unsigned r = (v.u + 0x7fffu + ((v.u >> 16) & 1u)) >> 16;
    return (unsigned short)r;
}
__device__ inline unsigned short f2bf_hw(float f) {   // HW RNE cvt (fast path)
    __hip_bfloat16 h = __float2bfloat16(f);
    return *reinterpret_cast<unsigned short*>(&h);
}
__device__ inline float bf2f(unsigned short u) {
    union { unsigned u; float f; } v; v.u = ((unsigned)u) << 16;
    return v.f;
}

#define GLL16(gp, lp) __builtin_amdgcn_global_load_lds( \
    (const __attribute__((address_space(1))) void*)(gp), \
    (__attribute__((address_space(3))) void*)(lp), 16, 0, 0)

// ---------------- fused prep: BT1 (BN-folded) | BT2 | b1' | degree count --------
__global__ __launch_bounds__(256) void prep_fused(
    const float* __restrict__ W1l, const float* __restrict__ W1r,
    const float* __restrict__ gamma, const float* __restrict__ beta,
    const float* __restrict__ mean, const float* __restrict__ var,
    const float* __restrict__ b1, unsigned short* __restrict__ BT,
    const float* __restrict__ W2l, const float* __restrict__ W2r,
    unsigned short* __restrict__ BT2, float* __restrict__ b1p,
    const int* __restrict__ ei, int* __restrict__ cnt, int E)
{
    const int bb = blockIdx.x;
    if (bb < 1024) {
        int idx = bb * 256 + threadIdx.x;
        int c  = idx >> 8;
        int k0 = (idx & 255) << 3;
        int cc = (c < 512) ? c : c - 512;
        float scv = gamma[cc] * rsqrtf(var[cc] + BN_EPS);
        const float* W = (c < 512) ? (W1l + cc) : (W1r + cc);
        unsigned short us[8];
#pragma unroll
        for (int j = 0; j < 8; ++j) {
            int k = k0 + j;
            float v = (k < GK) ? W[(size_t)k * 512] * scv : 0.0f;
            us[j] = f2bf(v);
        }
        *(u16x8*)&BT[(size_t)c * KP + k0] = *(u16x8*)us;
    } else if (bb < 1056) {
        int idx = (bb - 1024) * 256 + threadIdx.x;
        int c  = idx >> 6;
        int k0 = (idx & 63) << 3;
        const float* W = (c < 64) ? (W2l + c) : (W2r + (c - 64));
        unsigned short us[8];
#pragma unroll
        for (int j = 0; j < 8; ++j) us[j] = f2bf(W[(size_t)(k0 + j) * 64]);
        *(u16x8*)&BT2[(size_t)c * 512 + k0] = *(u16x8*)us;
    } else if (bb == 1056) {
#pragma unroll
        for (int h = 0; h < 2; ++h) {
            int c = threadIdx.x + h * 256;
            float scv = gamma[c] * rsqrtf(var[c] + BN_EPS);
            b1p[c] = b1[c] * scv + (beta[c] - mean[c] * scv);
        }
    } else {
        for (int i = (bb - 1057) * 256 + threadIdx.x; i < E; i += 1024 * 256)
            atomicAdd(&cnt[ei[E + i]], 1);
    }
}

// ---------------- exclusive scan over N counts (single block) ----------------
__global__ __launch_bounds__(1024) void scan_kernel(const int* __restrict__ cnt,
                                                    int* __restrict__ row_start, int n) {
    __shared__ int part[1024];
    int t = threadIdx.x;
    int chunk = (n + 1023) >> 10;
    int lo = t * chunk;
    int hi = lo + chunk; if (hi > n) hi = n;
    int s = 0;
    for (int i = lo; i < hi; ++i) s += cnt[i];
    part[t] = s;
    __syncthreads();
    for (int off = 1; off < 1024; off <<= 1) {
        int add = (t >= off) ? part[t - off] : 0;
        __syncthreads();
        part[t] += add;
        __syncthreads();
    }
    int run = (t == 0) ? 0 : part[t - 1];
    for (int i = lo; i < hi; ++i) { row_start[i] = run; run += cnt[i]; }
    if (t == 1023) row_start[n] = part[1023];
}

// ---------------- CSR fill (consumes cnt via atomicSub) ----------------
__global__ void fill_kernel(const int* __restrict__ ei, int E,
                            const int* __restrict__ row_start,
                            int* __restrict__ cnt, int* __restrict__ colidx) {
    int i = blockIdx.x * blockDim.x + threadIdx.x;
    if (i < E) {
        int d = ei[E + i];
        int p = atomicSub(&cnt[d], 1) - 1;
        colidx[row_start[d] + p] = ei[i];   // src
    }
}

// ---------------- GEMM1: Y = x(f32) @ BT^T — f32-A via GLL, 256x256, 3-ring -----
// A in LDS as f32 [256][32] (128B rows, 8x16B slots); phys slot s of row r holds
// logical granule s^(r&7). B as bf16 (round-9 swizzle). Per iter: vmcnt(6) ->
// barrier -> ds_read (16 A-b128 + 4 B-b128) -> cvt A f32->bf16 -> stage it+2
// (4 A-GLL + 2 B-GLL) -> 32 MFMA. Identical schedule to round-9 proven kernel.
__global__ __launch_bounds__(512) void gemm1_256(
    const float* __restrict__ x, int M,
    const unsigned short* __restrict__ BT,
    unsigned short* __restrict__ Y)
{
    __shared__ __align__(16) float          As[3][8192];   // 256 x 32 f32 = 32KB
    __shared__ __align__(16) unsigned short Bs[3][8192];   // 256 x 32 bf16 = 16KB

    const int t = threadIdx.x, wid = t >> 6, lane = t & 63;
    const int nbr = (M + 255) >> 8;
    const int nwg = nbr * 4;
    const int b   = blockIdx.x;
    int swz;
    if ((nwg & 7) == 0) swz = (b & 7) * (nwg >> 3) + (b >> 3);
    else swz = b;
    const int row0 = (swz >> 2) << 8;
    const int col0 = (swz & 3) << 8;

    // ---- A staging: 2048 chunks of 16B (4 f32). chunk c -> row=c>>3, slot=c&7,
    //      source logical granule g = (c&7)^((c>>3)&7), f32 offset g*4.
    int   cA[4];
    const float* aP[4];
    int   aOmax[4];
#pragma unroll
    for (int j = 0; j < 4; ++j) {
        int c = t + 512 * j;
        cA[j] = c;
        int row = row0 + (c >> 3); if (row >= M) row = M - 1;
        int g = (c & 7) ^ ((c >> 3) & 7);
        aP[j] = x + (size_t)row * GK + g * 4;
        aOmax[j] = 1996 - g * 4;   // clamp: only k>=2000 positions affected
    }

    // ---- B staging (round-9): chunks c in {t, t+512}; row=c>>2, slot=c&3
    const int cb0 = t, cb1 = t + 512;
    const int gb0 = ((cb0 & 3) ^ ((cb0 >> 3) & 3)) << 3;   // bf16 elems
    const int gb1 = ((cb1 & 3) ^ ((cb1 >> 3) & 3)) << 3;
    const unsigned short* bS0 = BT + (size_t)(col0 + (cb0 >> 2)) * KP + gb0;
    const unsigned short* bS1 = BT + (size_t)(col0 + (cb1 >> 2)) * KP + gb1;

    const int wr = wid >> 2, wc = wid & 3;   // 2 x 4 wave grid
    const int fr16 = lane & 15;
    // B read offset (round-9, 4-slot swizzle)
    const int gswr = ((lane >> 4) ^ ((fr16 >> 1) & 3)) << 4;
    // A read offsets (8-slot swizzle): j0 = (lane>>4)*2, s0 = j0^(fr16&7)
    const int offA0 = (((lane >> 4) * 2) ^ (fr16 & 7)) << 4;
    const int offA1 = offA0 ^ 16;

    f32x4 acc[8][4];
#pragma unroll
    for (int m = 0; m < 8; ++m)
#pragma unroll
        for (int n = 0; n < 4; ++n) acc[m][n] = (f32x4)0.0f;

#define STG(kt, buf) do {                                               \
        float* ab_ = &As[buf][0];                                       \
        unsigned short* bb_ = &Bs[buf][0];                              \
        _Pragma("unroll")                                               \
        for (int j_ = 0; j_ < 4; ++j_) {                                \
            int o_ = (kt) * 32; if (o_ > aOmax[j_]) o_ = aOmax[j_];     \
            GLL16(aP[j_] + o_, ab_ + cA[j_] * 4);                       \
        }                                                               \
        GLL16(bS0 + (size_t)(kt) * 32, bb_ + cb0 * 8);                  \
        GLL16(bS1 + (size_t)(kt) * 32, bb_ + cb1 * 8);                  \
    } while (0)

    // prologue: stage tiles 0 and 1 (12 loads/thread outstanding)
    STG(0, 0);
    STG(1, 1);

    int rb = 0;   // ring slot = it % 3
    for (int it = 0; it < NT1; ++it) {
        // wait tile-it's 6 oldest loads; tile it+1's 6 stay in flight
        if (it == NT1 - 1) {
            asm volatile("s_waitcnt vmcnt(0)" ::: "memory");
        } else {
            asm volatile("s_waitcnt vmcnt(6)" ::: "memory");
        }
        __builtin_amdgcn_s_barrier();
        __builtin_amdgcn_sched_barrier(0);

        const char* Ab = (const char*)&As[rb][0];
        const char* Bb = (const char*)&Bs[rb][0];

        bf16x8 af[8], bfr[4];
#pragma unroll
        for (int m = 0; m < 8; ++m) {
            int rowb = (wr * 128 + m * 16 + fr16) << 7;   // 128B rows
            f32x4 lo = *(const f32x4*)(Ab + rowb + offA0);
            f32x4 hi = *(const f32x4*)(Ab + rowb + offA1);
            unsigned short us[8];
            us[0] = f2bf_hw(lo[0]); us[1] = f2bf_hw(lo[1]);
            us[2] = f2bf_hw(lo[2]); us[3] = f2bf_hw(lo[3]);
            us[4] = f2bf_hw(hi[0]); us[5] = f2bf_hw(hi[1]);
            us[6] = f2bf_hw(hi[2]); us[7] = f2bf_hw(hi[3]);
            af[m] = *(bf16x8*)us;
        }
#pragma unroll
        for (int n = 0; n < 4; ++n)
            bfr[n] = *(const bf16x8*)(Bb + ((wc * 64 + n * 16 + fr16) << 6) + gswr);

        if (it + 2 < NT1) {
            int wb = rb + 2; if (wb >= 3) wb -= 3;
            STG(it + 2, wb);
        }

        __builtin_amdgcn_s_setprio(1);
#pragma unroll
        for (int m = 0; m < 8; ++m)
#pragma unroll
            for (int n = 0; n < 4; ++n)
                acc[m][n] = __builtin_amdgcn_mfma_f32_16x16x32_bf16(
                    af[m], bfr[n], acc[m][n], 0, 0, 0);
        __builtin_amdgcn_s_setprio(0);

        rb = (rb == 2) ? 0 : rb + 1;
    }
#undef STG

    const int crow = (lane >> 4) << 2;
#pragma unroll
    for (int m = 0; m < 8; ++m) {
        int rbase = row0 + wr * 128 + m * 16 + crow;
#pragma unroll
        for (int r = 0; r < 4; ++r) {
            int row = rbase + r;
            if (row < M) {
                unsigned short* Yp = Y + (size_t)row * 1024 + col0 + wc * 64 + fr16;
#pragma unroll
                for (int n = 0; n < 4; ++n)
                    Yp[n * 16] = f2bf(acc[m][n][r]);
            }
        }
    }
}

// ---------------- agg1: mean-gather(Yl) + b1' + self(Yr) + ReLU -> h (bf16) ------
__global__ __launch_bounds__(256) void agg1_kernel(
    const unsigned short* __restrict__ Y, unsigned short* __restrict__ Hh,
    const int* __restrict__ row_start, const int* __restrict__ colidx,
    const float* __restrict__ b1p, int n)
{
    int wid  = (blockIdx.x * blockDim.x + threadIdx.x) >> 6;
    int lane = threadIdx.x & 63;
    if (wid >= n) return;
    int c0 = lane * 8;
    float bb[8];
    *(float4*)&bb[0] = *(const float4*)&b1p[c0];
    *(float4*)&bb[4] = *(const float4*)&b1p[c0 + 4];

    int s0 = row_start[wid], s1 = row_start[wid + 1];
    float acc[8] = {0, 0, 0, 0, 0, 0, 0, 0};
    int i = s0;
    for (; i + 2 <= s1; i += 2) {
        int src0 = colidx[i], src1 = colidx[i + 1];
        u16x8 v0 = *(const u16x8*)&Y[(size_t)src0 * 1024 + c0];
        u16x8 v1 = *(const u16x8*)&Y[(size_t)src1 * 1024 + c0];
#pragma unroll
        for (int j = 0; j < 8; ++j) acc[j] += bf2f(v0[j]) + bf2f(v1[j]);
    }
    if (i < s1) {
        int src = colidx[i];
        u16x8 v = *(const u16x8*)&Y[(size_t)src * 1024 + c0];
#pragma unroll
        for (int j = 0; j < 8; ++j) acc[j] += bf2f(v[j]);
    }
    float inv = 1.0f / fmaxf((float)(s1 - s0), 1.0f);
    u16x8 sv = *(const u16x8*)&Y[(size_t)wid * 1024 + 512 + c0];
    unsigned short o[8];
#pragma unroll
    for (int j = 0; j < 8; ++j) {
        float pre = acc[j] * inv + bb[j] + bf2f(sv[j]);
        o[j] = f2bf(fmaxf(pre, 0.0f));
    }
    *(u16x8*)&Hh[(size_t)wid * 512 + c0] = *(u16x8*)o;
}

// ---------------- GEMM2: U[M x 128](bf16) = h[M x 512](bf16) @ BT2^T ------------
__global__ __launch_bounds__(256) void gemm2_bf16(
    const unsigned short* __restrict__ Hh, int M,
    const unsigned short* __restrict__ BT2,
    unsigned short* __restrict__ U)
{
    __shared__ __align__(16) unsigned short As[2][128][32];
    __shared__ __align__(16) unsigned short Bs[2][128][32];

    const int t    = threadIdx.x;
    const int wid  = t >> 6;
    const int lane = t & 63;
    const int row0 = blockIdx.x << 7;

    const int c_lo = wid * 64 + lane;
    const int c_hi = c_lo + 256;
    const int s_lo = ((c_lo & 3) ^ ((c_lo >> 3) & 3)) << 3;
    const int s_hi = ((c_hi & 3) ^ ((c_hi >> 3) & 3)) << 3;
    int ra = row0 + (c_lo >> 2); if (ra >= M) ra = M - 1;
    int rbw = row0 + (c_hi >> 2); if (rbw >= M) rbw = M - 1;
    const unsigned short* aSrc0 = Hh + (size_t)ra * 512 + s_lo;
    const unsigned short* aSrc1 = Hh + (size_t)rbw * 512 + s_hi;
    const unsigned short* bSrc0 = BT2 + (size_t)(c_lo >> 2) * 512 + s_lo;
    const unsigned short* bSrc1 = BT2 + (size_t)(c_hi >> 2) * 512 + s_hi;

    const int wr   = wid >> 1, wc = wid & 1;
    const int fr16 = lane & 15;
    const int gsw2 = ((lane >> 4) ^ ((fr16 >> 1) & 3)) << 4;

    f32x4 acc[4][4];
#pragma unroll
    for (int m = 0; m < 4; ++m)
#pragma unroll
        for (int n = 0; n < 4; ++n) acc[m][n] = (f32x4)0.0f;

#define STAGE2(kt, buf) do {                                                  \
        int ko = (kt) * 32;                                                   \
        GLL16(aSrc0 + ko, (unsigned short*)&As[buf][0][0] + (size_t)c_lo * 8);  \
        GLL16(aSrc1 + ko, (unsigned short*)&As[buf][0][0] + (size_t)c_hi * 8);  \
        GLL16(bSrc0 + ko, (unsigned short*)&Bs[buf][0][0] + (size_t)c_lo * 8);  \
        GLL16(bSrc1 + ko, (unsigned short*)&Bs[buf][0][0] + (size_t)c_hi * 8);  \
    } while (0)

    STAGE2(0, 0);
    int cur = 0;
    for (int it = 0; it < NT2; ++it) {
        __syncthreads();
        if (it + 1 < NT2) STAGE2(it + 1, cur ^ 1);

        const char* Ab = (const char*)&As[cur][0][0];
        const char* Bb = (const char*)&Bs[cur][0][0];
        bf16x8 af[4], bfr[4];
#pragma unroll
        for (int m = 0; m < 4; ++m)
            af[m] = *(const bf16x8*)(Ab + ((wr * 64 + m * 16 + fr16) << 6) + gsw2);
#pragma unroll
        for (int n = 0; n < 4; ++n)
            bfr[n] = *(const bf16x8*)(Bb + ((wc * 64 + n * 16 + fr16) << 6) + gsw2);
#pragma unroll
        for (int m = 0; m < 4; ++m)
#pragma unroll
            for (int n = 0; n < 4; ++n)
                acc[m][n] = __builtin_amdgcn_mfma_f32_16x16x32_bf16(
                    af[m], bfr[n], acc[m][n], 0, 0, 0);
        cur ^= 1;
    }
#undef STAGE2

    const int crow = (lane >> 4) << 2;
#pragma unroll
    for (int m = 0; m < 4; ++m) {
        int rbase = row0 + wr * 64 + m * 16 + crow;
#pragma unroll
        for (int r = 0; r < 4; ++r) {
            int row = rbase + r;
            if (row < M) {
                unsigned short* Up = U + (size_t)row * 128 + wc * 64 + fr16;
#pragma unroll
                for (int n = 0; n < 4; ++n)
                    Up[n * 16] = f2bf(acc[m][n][r]);
            }
        }
    }
}

// ---------------- agg2: mean-gather(Ul) + b2 + self(Ur) -> out (f32) ----------------
__global__ __launch_bounds__(256) void agg2_kernel(
    const unsigned short* __restrict__ U,
    const int* __restrict__ row_start, const int* __restrict__ colidx,
    const float* __restrict__ b2, float* __restrict__ out, int n)
{
    int wid  = (blockIdx.x * blockDim.x + threadIdx.x) >> 6;
    int lane = threadIdx.x & 63;
    if (wid >= n) return;
    int s0 = row_start[wid], s1 = row_start[wid + 1];
    float acc = 0.f;
    int i = s0;
    for (; i + 2 <= s1; i += 2) {
        int src0 = colidx[i], src1 = colidx[i + 1];
        acc += bf2f(U[(size_t)src0 * 128 + lane]) + bf2f(U[(size_t)src1 * 128 + lane]);
    }
    if (i < s1) acc += bf2f(U[(size_t)colidx[i] * 128 + lane]);
    float inv = 1.0f / fmaxf((float)(s1 - s0), 1.0f);
    float z = acc * inv + b2[lane] + bf2f(U[(size_t)wid * 128 + 64 + lane]);
    out[(size_t)wid * 64 + lane] = z;
}

extern "C" void kernel_launch(void* const* d_in, const int* in_sizes, int n_in,
                              void* d_out, int out_size, void* d_ws, size_t ws_size,
                              hipStream_t stream) {
    const float* x     = (const float*)d_in[0];
    const int*   ei    = (const int*)d_in[1];
    const float* W1l   = (const float*)d_in[2];
    const float* b1    = (const float*)d_in[3];
    const float* W1r   = (const float*)d_in[4];
    const float* gamma = (const float*)d_in[5];
    const float* beta  = (const float*)d_in[6];
    const float* mean  = (const float*)d_in[7];
    const float* var   = (const float*)d_in[8];
    const float* W2l   = (const float*)d_in[9];
    const float* b2    = (const float*)d_in[10];
    const float* W2r   = (const float*)d_in[11];
    float* out = (float*)d_out;

    const int N = in_sizes[0] / 2000;   // 50000
    const int E = in_sizes[1] / 2;      // 800000
    const int nby = (N + 127) / 128;

    // Workspace (~161 MB): Y | Hh | BT | BT2 | b1p | cnt | row_start | colidx
    //   (U aliases Y after agg1)
    char* ws = (char*)d_ws;
    unsigned short* Y   = (unsigned short*)ws;
    unsigned short* Hh  = Y + (size_t)N * 1024;
    unsigned short* BT  = Hh + (size_t)N * 512;
    unsigned short* BT2 = BT + (size_t)1024 * KP;
    float* b1p     = (float*)(BT2 + (size_t)128 * 512);
    int* cnt       = (int*)(b1p + 512);
    int* row_start = cnt + N;
    int* colidx    = row_start + N + 4;
    unsigned short* U = Y;   // alias: Y dead after agg1

    hipMemsetAsync(cnt, 0, (size_t)N * sizeof(int), stream);

    prep_fused<<<2081, 256, 0, stream>>>(
        W1l, W1r, gamma, beta, mean, var, b1, BT, W2l, W2r, BT2, b1p,
        ei, cnt, E);

    scan_kernel<<<1, 1024, 0, stream>>>(cnt, row_start, N);
    int eb = (E + 255) / 256;
    fill_kernel<<<eb, 256, 0, stream>>>(ei, E, row_start, cnt, colidx);

    int nbr = (N + 255) / 256;
    gemm1_256<<<nbr * 4, 512, 0, stream>>>(x, N, BT, Y);
    agg1_kernel<<<(N + 3) / 4, 256, 0, stream>>>(
        Y, Hh, row_start, colidx, b1p, N);
    gemm2_bf16<<<nby, 256, 0, stream>>>(Hh, N, BT2, U);
    agg2_kernel<<<(N + 3) / 4, 256, 0, stream>>>(
        U, row_start, colidx, b2, out, N);
}